// Round 1
// baseline (929.893 us; speedup 1.0000x reference)
//
#include <hip/hip_runtime.h>

typedef unsigned short ushort;
typedef unsigned int uint;
typedef __bf16 bf16_t;
typedef bf16_t bf16x8 __attribute__((ext_vector_type(8)));
typedef float f32x4 __attribute__((ext_vector_type(4)));

#define B_ 2048
#define T_ 512
#define D_ 5
#define H_ 128
#define C_ 10
#define BT 16      // batch tile per workgroup
#define BLK 512    // 8 waves, 2 waves/SIMD
#define NP 128     // producer/consumer pair count
#define CH 8       // pipeline chunk (steps per sync)
#define H0STR 168  // mono kernel: LDS row stride in ushorts (h0 row 128 + x cols + pad)
#define H1STR 136  // mono kernel: h1 row stride (128 + 8 pad)
#define SSTR 136   // pipe kernel: swizzled h row stride (128 + 8 pad, 272B = 17*16B)
#define XSTR 40    // pipe kernel: x-chunk row stride in ushorts (80B, 20dw -> spread banks)

static __device__ __forceinline__ float b2f(ushort u) {
    return __builtin_bit_cast(float, ((uint)u) << 16);
}
static __device__ __forceinline__ ushort f2b(float f) {
    uint u = __builtin_bit_cast(uint, f);
    u += 0x7FFFu + ((u >> 16) & 1u);   // RNE
    return (ushort)(u >> 16);
}
// inf-safe: exp->inf => rcp->0 => sigmoid->0/1, tanh->+-1
static __device__ __forceinline__ float sigf(float x) {
    return __builtin_amdgcn_rcpf(1.0f + __expf(-x));
}
static __device__ __forceinline__ float tanhf_(float x) {
    return 1.0f - 2.0f * __builtin_amdgcn_rcpf(1.0f + __expf(2.0f * x));
}
static __device__ __forceinline__ float ldf(const void* p, long i, bool m32) {
    return m32 ? ((const float*)p)[i] : b2f(((const ushort*)p)[i]);
}
static __device__ __forceinline__ bf16x8 ld16(const ushort* p) {
    return __builtin_bit_cast(bf16x8, *(const uint4*)p);
}
static __device__ __forceinline__ bf16x8 ldfrag(const void* p, long idx, bool m32) {
    if (!m32) return ld16((const ushort*)p + idx);
    const float* f = (const float*)p + idx;
    union { ushort u[8]; bf16x8 v; } r;
#pragma unroll
    for (int j = 0; j < 8; ++j) r.u[j] = f2b(f[j]);
    return r.v;
}
static __device__ __forceinline__ f32x4 splat4(float v) {
    f32x4 r = {v, v, v, v};
    return r;
}
// swizzled ushort index into a [16][SSTR] tile: XOR row bit3 into col block
// (breaks the 16q-bank aliasing of rows 4q+r on b16 writes; 2 lanes/bank = free)
static __device__ __forceinline__ int swz(int row, int col) {
    return row * SSTR + ((((col >> 4) ^ (row >> 3)) << 4) | (col & 15));
}
// lgkm-only barrier: LDS producer->consumer exchange without draining global
// stores (FIFO stores float until the chunk publish). Post-asm fences reads.
static __device__ __forceinline__ void bar_lds() {
    asm volatile("s_waitcnt lgkmcnt(0)" ::: "memory");
    __builtin_amdgcn_s_barrier();
    asm volatile("" ::: "memory");
}

// ---- dtype detector (proven R2-R5; picks f32)
__global__ void detect_dtype(const ushort* __restrict__ w, int* __restrict__ flag) {
    __shared__ int cnt;
    if (threadIdx.x == 0) cnt = 0;
    __syncthreads();
    int local = 0;
    for (int i = threadIdx.x; i < 16384; i += 256)
        if ((uint)(w[i] & 0x7F80u) >= 0x4180u) ++local;   // |v| >= 16
    atomicAdd(&cnt, local);
    __syncthreads();
    if (threadIdx.x == 0) *flag = (cnt > 512) ? 1 : 0;
}

// ---- zero the pipeline progress flags (d_ws is poisoned before each launch)
__global__ void init_flags(int* __restrict__ prog) {
    prog[threadIdx.x] = 0;   // 256 ints: prog_p[128], prog_c[128]
}

// =====================================================================
// Pipelined kernel: block p<NP = layer-0 producer; block NP+p = layer-1
// consumer + classifier. h0 streamed via ring FIFO (F slots) in d_ws.
// =====================================================================
__global__ __launch_bounds__(BLK, 2) void lstm2_pipe(
    const void* __restrict__ x,
    const void* __restrict__ wih0, const void* __restrict__ whh0,
    const void* __restrict__ bih0, const void* __restrict__ bhh0,
    const void* __restrict__ wih1, const void* __restrict__ whh1,
    const void* __restrict__ bih1, const void* __restrict__ bhh1,
    const void* __restrict__ cw1, const void* __restrict__ cb1,
    const void* __restrict__ cw2, const void* __restrict__ cb2,
    const int* __restrict__ flag,
    ushort* __restrict__ fifo, int* __restrict__ prog_p, int* __restrict__ prog_c,
    int F, void* __restrict__ out)
{
    __shared__ __align__(16) ushort sA[2][BT * SSTR];       // prod: h0 xpose; cons: staged h0
    __shared__ __align__(16) ushort sB[2][BT * SSTR];       // cons: h1 recurrence
    __shared__ __align__(16) ushort xch[CH * 16 * XSTR];    // prod: x chunk ring
    __shared__ float rs[BT * 64];                           // cons: classifier hidden

    const bool m32 = (*flag) != 0;
    const int tid  = threadIdx.x;
    const int w    = tid >> 6;
    const int lane = tid & 63;
    const int quad = lane >> 4;
    const int l16  = lane & 15;

    if ((int)blockIdx.x < NP) {
        // ================= PRODUCER: layer 0 =================
        const int p   = blockIdx.x;
        const int bt0 = p * BT;
        ushort* myfifo = fifo + (long)p * F * (BT * H_);

        // x chunk-prefetch mapping (thread-invariant): elem e = r*40 + tt*5 + d
        const int e0 = tid;
        const int r0 = e0 / 40, rem0 = e0 - r0 * 40;
        const int tt0 = rem0 / 5, d0 = rem0 - tt0 * 5;
        const long xo0 = (long)(bt0 + r0) * T_ * D_ + (long)tt0 * D_ + d0;
        const int xdst0 = (tt0 * 16 + r0) * XSTR + d0;
        const int e1 = tid + 512;
        const int r1 = e1 / 40, rem1 = e1 - r1 * 40;
        const int tt1 = rem1 / 5, d1 = rem1 - tt1 * 5;
        const long xo1 = (long)(bt0 + r1) * T_ * D_ + (long)tt1 * D_ + d1;
        const int xdst1 = (tt1 * 16 + r1) * XSTR + d1;
        const bool has1 = (tid < 128);   // 640 = 512 + 128 elems per chunk

        // zero xch once: cols 5..39 stay zero forever (MFMA K-padding)
        for (int i = tid; i < CH * 16 * XSTR; i += BLK) xch[i] = 0;

        // weights: w_hh0 frags + x-tile frags (registers/AGPRs)
        bf16x8 wh0c[4][4];
        bf16x8 xbf[4];
        float  b0v[4];
#pragma unroll
        for (int g = 0; g < 4; ++g) {
            const int n = g * 128 + w * 16 + l16;
#pragma unroll
            for (int kt = 0; kt < 4; ++kt)
                wh0c[g][kt] = ldfrag(whh0, (long)n * 128 + kt * 32 + quad * 8, m32);
            union { ushort u[8]; bf16x8 v; } xt;
#pragma unroll
            for (int j = 0; j < 8; ++j) xt.u[j] = 0;
            if (quad == 0) {
#pragma unroll
                for (int j = 0; j < 5; ++j) xt.u[j] = f2b(ldf(wih0, (long)n * D_ + j, m32));
            }
            xbf[g] = xt.v;
            b0v[g] = ldf(bih0, n, m32) + ldf(bhh0, n, m32);
        }
        __syncthreads();    // xch zero-init done

        // chunk 0 -> LDS, chunk 1 -> prefetch regs
        {
            float v0 = ldf(x, xo0, m32);
            float v1 = has1 ? ldf(x, xo1, m32) : 0.f;
            xch[xdst0] = f2b(v0);
            if (has1) xch[xdst1] = f2b(v1);
        }
        float xp0 = ldf(x, xo0 + (long)(CH * D_), m32);                 // t=8..15: always in range
        float xp1 = has1 ? ldf(x, xo1 + (long)(CH * D_), m32) : 0.f;
        __syncthreads();    // chunk-0 fill done

        bf16x8 h0f[4];
        {
            uint4 z = make_uint4(0, 0, 0, 0);
            h0f[0] = h0f[1] = h0f[2] = h0f[3] = __builtin_bit_cast(bf16x8, z);
        }
        f32x4 c0 = splat4(0.f);

#pragma unroll 1
        for (int t = 0; t < T_; ++t) {
            const int wb = (t + 1) & 1;
            if ((t & (CH - 1)) == 0 && t > 0) {
                // (A) full drain: all waves' FIFO stores of steps < t are in L2
                __syncthreads();
                // fill x chunk t/CH from prefetch regs (old chunk's reads done pre-(A))
                xch[xdst0] = f2b(xp0);
                if (has1) xch[xdst1] = f2b(xp1);
                if (tid == 0) {
                    // wbl2 in the release pushes every drained store; publish steps < t
                    __hip_atomic_store(&prog_p[p], t, __ATOMIC_RELEASE,
                                       __HIP_MEMORY_SCOPE_AGENT);
                    int need = t + CH - F;   // ring WAR throttle (relaxed: control-dep)
                    if (need > 0)
                        while (__hip_atomic_load(&prog_c[p], __ATOMIC_RELAXED,
                                                 __HIP_MEMORY_SCOPE_AGENT) < need)
                            __builtin_amdgcn_s_sleep(2);
                }
                // (B) xch fill visible + publish done (no outstanding vmem here)
                __syncthreads();
                // prefetch next chunk into regs (8 steps of cover)
                const int tb = t + CH;
                xp0 = (tb + tt0 < T_) ? ldf(x, xo0 + (long)tb * D_, m32) : 0.f;
                xp1 = (has1 && tb + tt1 < T_) ? ldf(x, xo1 + (long)tb * D_, m32) : 0.f;
            }

            f32x4 a[4];
#pragma unroll
            for (int g = 0; g < 4; ++g) a[g] = splat4(b0v[g]);
#pragma unroll
            for (int kt = 0; kt < 4; ++kt)
#pragma unroll
                for (int g = 0; g < 4; ++g)
                    a[g] = __builtin_amdgcn_mfma_f32_16x16x32_bf16(
                        h0f[kt], wh0c[g][kt], a[g], 0, 0, 0);
            {
                bf16x8 ha4 = ld16(&xch[((t & (CH - 1)) * 16 + l16) * XSTR + quad * 8]);
#pragma unroll
                for (int g = 0; g < 4; ++g)
                    a[g] = __builtin_amdgcn_mfma_f32_16x16x32_bf16(
                        ha4, xbf[g], a[g], 0, 0, 0);
            }
            ushort* fs = myfifo + (long)(t & (F - 1)) * (BT * H_);
#pragma unroll
            for (int r = 0; r < 4; ++r) {
                float iv = sigf(a[0][r]), fv = sigf(a[1][r]);
                float gv = tanhf_(a[2][r]), ov = sigf(a[3][r]);
                float cv = fv * c0[r] + iv * gv;
                c0[r] = cv;
                ushort hv = f2b(ov * tanhf_(cv));
                int row = quad * 4 + r;
                sA[wb][swz(row, w * 16 + l16)] = hv;
                fs[row * H_ + w * 16 + l16] = hv;   // FIFO store: floats until chunk drain
            }
            bar_lds();   // lgkm-only: do NOT wait on FIFO store acks
#pragma unroll
            for (int kt = 0; kt < 4; ++kt)
                h0f[kt] = ld16(&sA[wb][swz(l16, kt * 32 + quad * 8)]);
        }
        // final publish: drain last chunk's stores across the block first
        __syncthreads();
        if (tid == 0)
            __hip_atomic_store(&prog_p[p], T_, __ATOMIC_RELEASE,
                               __HIP_MEMORY_SCOPE_AGENT);
    } else {
        // ================= CONSUMER: layer 1 + classifier =================
        const int p   = blockIdx.x - NP;
        const int bt0 = p * BT;
        const ushort* myfifo = fifo + (long)p * F * (BT * H_);

        // zero h1(-1) (linear zero covers the swizzled permutation)
        for (int i = tid; i < BT * SSTR; i += BLK) sB[0][i] = 0;

        // weights: w_ih1 + w_hh1 frags
        bf16x8 wi1f[4][4], wh1f[4][4];
        float  b1v[4];
#pragma unroll
        for (int g = 0; g < 4; ++g) {
            const int n = g * 128 + w * 16 + l16;
#pragma unroll
            for (int kt = 0; kt < 4; ++kt) {
                wi1f[g][kt] = ldfrag(wih1, (long)n * 128 + kt * 32 + quad * 8, m32);
                wh1f[g][kt] = ldfrag(whh1, (long)n * 128 + kt * 32 + quad * 8, m32);
            }
            b1v[g] = ldf(bih1, n, m32) + ldf(bhh1, n, m32);
        }

        // wait for first two chunks: relaxed spin, ONE acquire fence (inv) per wait
        if (tid == 0) {
            while (__hip_atomic_load(&prog_p[p], __ATOMIC_RELAXED,
                                     __HIP_MEMORY_SCOPE_AGENT) < 2 * CH)
                __builtin_amdgcn_s_sleep(2);
            __builtin_amdgcn_fence(__ATOMIC_ACQUIRE, "agent");
        }
        __syncthreads();
        {
            int row = tid >> 5, col4 = (tid & 31) * 4;
            uint2 d = *(const uint2*)(myfifo + tid * 4);
            *(uint2*)&sA[0][swz(row, col4)] = d;
        }
        __syncthreads();

        f32x4 c1 = splat4(0.f);

#pragma unroll 1
        for (int t = 0; t < T_; ++t) {
            const int rb = t & 1, wb = (t + 1) & 1;
            // chunk boundary BEFORE prefetching into the next chunk:
            // one acquire fence precedes every read of newly-ready slots.
            if (((t + 1) & (CH - 1)) == 0 && t + 1 < T_) {
                if (tid == 0) {
                    int target = t + 1 + CH;
                    if (target > T_) target = T_;
                    while (__hip_atomic_load(&prog_p[p], __ATOMIC_RELAXED,
                                             __HIP_MEMORY_SCOPE_AGENT) < target)
                        __builtin_amdgcn_s_sleep(2);
                    __builtin_amdgcn_fence(__ATOMIC_ACQUIRE, "agent");
                    __hip_atomic_store(&prog_c[p], t + 1, __ATOMIC_RELEASE,
                                       __HIP_MEMORY_SCOPE_AGENT);
                }
                __syncthreads();
            }
            // prefetch h0(t+1)
            uint2 pf = make_uint2(0, 0);
            const bool hn = (t + 1 < T_);
            if (hn) pf = *(const uint2*)(myfifo
                          + (long)((t + 1) & (F - 1)) * (BT * H_) + tid * 4);

            f32x4 a[4];
#pragma unroll
            for (int g = 0; g < 4; ++g) a[g] = splat4(b1v[g]);
#pragma unroll
            for (int kt = 0; kt < 4; ++kt) {
                bf16x8 h0a = ld16(&sA[rb][swz(l16, kt * 32 + quad * 8)]);
#pragma unroll
                for (int g = 0; g < 4; ++g)
                    a[g] = __builtin_amdgcn_mfma_f32_16x16x32_bf16(
                        h0a, wi1f[g][kt], a[g], 0, 0, 0);
            }
#pragma unroll
            for (int kt = 0; kt < 4; ++kt) {
                bf16x8 hb = ld16(&sB[rb][swz(l16, kt * 32 + quad * 8)]);
#pragma unroll
                for (int g = 0; g < 4; ++g)
                    a[g] = __builtin_amdgcn_mfma_f32_16x16x32_bf16(
                        hb, wh1f[g][kt], a[g], 0, 0, 0);
            }
#pragma unroll
            for (int r = 0; r < 4; ++r) {
                float iv = sigf(a[0][r]), fv = sigf(a[1][r]);
                float gv = tanhf_(a[2][r]), ov = sigf(a[3][r]);
                float cv = fv * c1[r] + iv * gv;
                c1[r] = cv;
                sB[wb][swz(quad * 4 + r, w * 16 + l16)] = f2b(ov * tanhf_(cv));
            }
            if (hn) {
                int row = tid >> 5, col4 = (tid & 31) * 4;
                *(uint2*)&sA[wb][swz(row, col4)] = pf;
            }
            bar_lds();
        }

        // h1(T-1) is in sB[0]  (t=511: wb=0)
        if (tid < 256) {
            int m = tid >> 4, j0 = (tid & 15) * 4;
            float s0 = ldf(cb1, j0, m32), s1 = ldf(cb1, j0 + 1, m32);
            float s2 = ldf(cb1, j0 + 2, m32), s3 = ldf(cb1, j0 + 3, m32);
            const int mswz = m >> 3;
#pragma unroll
            for (int kb = 0; kb < 8; ++kb) {
                const ushort* hp = &sB[0][m * SSTR + ((kb ^ mswz) << 4)];
#pragma unroll
                for (int kk = 0; kk < 16; ++kk) {
                    int k = kb * 16 + kk;
                    float hv = b2f(hp[kk]);
                    s0 += hv * ldf(cw1, (long)j0 * 128 + k, m32);
                    s1 += hv * ldf(cw1, (long)(j0 + 1) * 128 + k, m32);
                    s2 += hv * ldf(cw1, (long)(j0 + 2) * 128 + k, m32);
                    s3 += hv * ldf(cw1, (long)(j0 + 3) * 128 + k, m32);
                }
            }
            rs[m * 64 + j0]     = fmaxf(s0, 0.f);
            rs[m * 64 + j0 + 1] = fmaxf(s1, 0.f);
            rs[m * 64 + j0 + 2] = fmaxf(s2, 0.f);
            rs[m * 64 + j0 + 3] = fmaxf(s3, 0.f);
        }
        __syncthreads();
        if (tid < 160) {
            int m = tid / 10, cc = tid - m * 10;
            float s = ldf(cb2, cc, m32);
#pragma unroll
            for (int j = 0; j < 64; ++j)
                s += rs[m * 64 + j] * ldf(cw2, (long)cc * 64 + j, m32);
            long oi = (long)(bt0 + m) * C_ + cc;
            if (m32) ((float*)out)[oi] = s; else ((ushort*)out)[oi] = f2b(s);
        }
        for (int idx = tid; idx < BT * H_; idx += BLK) {
            int m = idx >> 7, k = idx & 127;
            float v = b2f(sB[0][swz(m, k)]);
            long oi = (long)B_ * C_ + (long)(bt0 + m) * H_ + k;
            if (m32) ((float*)out)[oi] = v; else ((ushort*)out)[oi] = f2b(v);
        }
    }
}

// =====================================================================
// Fallback: proven R5 monolithic kernel (used when ws too small for FIFO)
// =====================================================================
__global__ __launch_bounds__(BLK, 2) void lstm2_mono(
    const void* __restrict__ x,
    const void* __restrict__ wih0, const void* __restrict__ whh0,
    const void* __restrict__ bih0, const void* __restrict__ bhh0,
    const void* __restrict__ wih1, const void* __restrict__ whh1,
    const void* __restrict__ bih1, const void* __restrict__ bhh1,
    const void* __restrict__ cw1, const void* __restrict__ cb1,
    const void* __restrict__ cw2, const void* __restrict__ cb2,
    const int* __restrict__ flag, void* __restrict__ out)
{
    __shared__ __align__(16) ushort h0s[2][BT * H0STR];
    __shared__ __align__(16) ushort h1s[2][BT * H1STR];
    __shared__ float rs[BT * 64];
    __shared__ uint4 xstash[4 * 8 * 64];

    const bool m32 = (*flag) != 0;
    const int tid  = threadIdx.x;
    const int w    = tid >> 6;
    const int lane = tid & 63;
    const int quad = lane >> 4;
    const int l16  = lane & 15;
    const int bt0  = blockIdx.x * BT;

    for (int i = tid; i < BT * 32; i += BLK) {
        int row = i >> 5, cc = i & 31;
        ushort v0 = (cc < 5) ? f2b(ldf(x, ((long)(bt0 + row) * T_) * D_ + cc, m32)) : (ushort)0;
        h0s[0][row * H0STR + 128 + cc] = v0;
        h0s[1][row * H0STR + 128 + cc] = 0;
    }
    for (int i = tid; i < BT * H_; i += BLK) {
        int row = i >> 7, cc = i & 127;
        h1s[1][row * H1STR + cc] = 0;
    }

    bf16x8 wh0c[4][4], wi1f[4][4], wh1f[4][4];
    float  b0v[4], b1v[4];
#pragma unroll
    for (int g = 0; g < 4; ++g) {
        const int n = g * 128 + w * 16 + l16;
#pragma unroll
        for (int kt = 0; kt < 4; ++kt) {
            wh0c[g][kt] = ldfrag(whh0, (long)n * 128 + kt * 32 + quad * 8, m32);
            wi1f[g][kt] = ldfrag(wih1, (long)n * 128 + kt * 32 + quad * 8, m32);
            wh1f[g][kt] = ldfrag(whh1, (long)n * 128 + kt * 32 + quad * 8, m32);
        }
        union { ushort u[8]; uint4 q; } xt;
        xt.q = make_uint4(0, 0, 0, 0);
        if (quad == 0) {
#pragma unroll
            for (int j = 0; j < 5; ++j) xt.u[j] = f2b(ldf(wih0, (long)n * D_ + j, m32));
        }
        xstash[(g * 8 + w) * 64 + lane] = xt.q;
        b0v[g] = ldf(bih0, n, m32) + ldf(bhh0, n, m32);
        b1v[g] = ldf(bih1, n, m32) + ldf(bhh1, n, m32);
    }
    __syncthreads();

    bf16x8 h0f[4];
    {
        uint4 z = make_uint4(0, 0, 0, 0);
        h0f[0] = h0f[1] = h0f[2] = h0f[3] = __builtin_bit_cast(bf16x8, z);
    }
    f32x4 c0 = splat4(0.f), c1 = splat4(0.f);
    const int xr = tid / 5, xc = tid - (tid / 5) * 5;

#pragma unroll 1
    for (int t = 0; t < T_; ++t) {
        const int wb = (t + 1) & 1, rb = t & 1;
        float xv = 0.f;
        const bool stage = (tid < 80) && (t < T_ - 1);
        if (stage) xv = ldf(x, ((long)(bt0 + xr) * T_ + (t + 1)) * D_ + xc, m32);

        f32x4 a[4];
#pragma unroll
        for (int g = 0; g < 4; ++g) a[g] = splat4(b0v[g]);
#pragma unroll
        for (int kt = 0; kt < 4; ++kt)
#pragma unroll
            for (int g = 0; g < 4; ++g)
                a[g] = __builtin_amdgcn_mfma_f32_16x16x32_bf16(
                    h0f[kt], wh0c[g][kt], a[g], 0, 0, 0);
        {
            bf16x8 ha4 = ld16(&h0s[rb][l16 * H0STR + 128 + quad * 8]);
#pragma unroll
            for (int g = 0; g < 4; ++g) {
                bf16x8 xb = __builtin_bit_cast(bf16x8, xstash[(g * 8 + w) * 64 + lane]);
                a[g] = __builtin_amdgcn_mfma_f32_16x16x32_bf16(ha4, xb, a[g], 0, 0, 0);
            }
        }
        ushort h0w[4];
#pragma unroll
        for (int r = 0; r < 4; ++r) {
            float iv = sigf(a[0][r]), fv = sigf(a[1][r]);
            float gv = tanhf_(a[2][r]), ov = sigf(a[3][r]);
            float cv = fv * c0[r] + iv * gv;
            c0[r] = cv;
            h0w[r] = f2b(ov * tanhf_(cv));
        }
#pragma unroll
        for (int r = 0; r < 4; ++r)
            h0s[wb][(quad * 4 + r) * H0STR + w * 16 + l16] = h0w[r];
        if (stage) h0s[wb][xr * H0STR + 128 + xc] = f2b(xv);
        __syncthreads();
#pragma unroll
        for (int kt = 0; kt < 4; ++kt)
            h0f[kt] = ld16(&h0s[wb][l16 * H0STR + kt * 32 + quad * 8]);

#pragma unroll
        for (int g = 0; g < 4; ++g) a[g] = splat4(b1v[g]);
#pragma unroll
        for (int kt = 0; kt < 4; ++kt)
#pragma unroll
            for (int g = 0; g < 4; ++g)
                a[g] = __builtin_amdgcn_mfma_f32_16x16x32_bf16(
                    h0f[kt], wi1f[g][kt], a[g], 0, 0, 0);
#pragma unroll
        for (int kt = 0; kt < 4; ++kt) {
            bf16x8 hb = ld16(&h1s[wb][l16 * H1STR + kt * 32 + quad * 8]);
#pragma unroll
            for (int g = 0; g < 4; ++g)
                a[g] = __builtin_amdgcn_mfma_f32_16x16x32_bf16(
                    hb, wh1f[g][kt], a[g], 0, 0, 0);
        }
#pragma unroll
        for (int r = 0; r < 4; ++r) {
            float iv = sigf(a[0][r]), fv = sigf(a[1][r]);
            float gv = tanhf_(a[2][r]), ov = sigf(a[3][r]);
            float cv = fv * c1[r] + iv * gv;
            c1[r] = cv;
            h1s[wb ^ 1][(quad * 4 + r) * H1STR + w * 16 + l16] = f2b(ov * tanhf_(cv));
        }
    }
    __syncthreads();

    if (tid < 256) {
        int m = tid >> 4, j0 = (tid & 15) * 4;
        float s0 = ldf(cb1, j0, m32), s1 = ldf(cb1, j0 + 1, m32);
        float s2 = ldf(cb1, j0 + 2, m32), s3 = ldf(cb1, j0 + 3, m32);
        const ushort* hr = &h1s[1][m * H1STR];
#pragma unroll 4
        for (int k = 0; k < 128; ++k) {
            float hv = b2f(hr[k]);
            s0 += hv * ldf(cw1, (long)j0 * 128 + k, m32);
            s1 += hv * ldf(cw1, (long)(j0 + 1) * 128 + k, m32);
            s2 += hv * ldf(cw1, (long)(j0 + 2) * 128 + k, m32);
            s3 += hv * ldf(cw1, (long)(j0 + 3) * 128 + k, m32);
        }
        rs[m * 64 + j0]     = fmaxf(s0, 0.f);
        rs[m * 64 + j0 + 1] = fmaxf(s1, 0.f);
        rs[m * 64 + j0 + 2] = fmaxf(s2, 0.f);
        rs[m * 64 + j0 + 3] = fmaxf(s3, 0.f);
    }
    __syncthreads();
    if (tid < 160) {
        int m = tid / 10, cc = tid - m * 10;
        float s = ldf(cb2, cc, m32);
#pragma unroll
        for (int j = 0; j < 64; ++j) s += rs[m * 64 + j] * ldf(cw2, (long)cc * 64 + j, m32);
        long oi = (long)(bt0 + m) * C_ + cc;
        if (m32) ((float*)out)[oi] = s; else ((ushort*)out)[oi] = f2b(s);
    }
    for (int idx = tid; idx < BT * H_; idx += BLK) {
        int m = idx >> 7, k = idx & 127;
        float v = b2f(h1s[1][m * H1STR + k]);
        long oi = (long)B_ * C_ + (long)(bt0 + m) * H_ + k;
        if (m32) ((float*)out)[oi] = v; else ((ushort*)out)[oi] = f2b(v);
    }
}

extern "C" void kernel_launch(void* const* d_in, const int* in_sizes, int n_in,
                              void* d_out, int out_size, void* d_ws, size_t ws_size,
                              hipStream_t stream) {
    (void)in_sizes; (void)n_in; (void)out_size;
    int* prog  = (int*)d_ws;                       // prog_p[128] | prog_c[128]
    int* flag  = (int*)((char*)d_ws + 4096);
    ushort* fifo = (ushort*)((char*)d_ws + 8192);

    hipLaunchKernelGGL(detect_dtype, dim3(1), dim3(256), 0, stream,
                       (const ushort*)d_in[2], flag);

    const size_t slot = (size_t)NP * BT * H_ * sizeof(ushort); // all pairs, 1 step
    int F = 0;
    if (ws_size >= 8192 + 64 * slot) F = 64;
    else if (ws_size >= 8192 + 32 * slot) F = 32;

    if (F) {
        hipLaunchKernelGGL(init_flags, dim3(1), dim3(256), 0, stream, prog);
        hipLaunchKernelGGL(lstm2_pipe, dim3(2 * NP), dim3(BLK), 0, stream,
                           d_in[0], d_in[1], d_in[2], d_in[3], d_in[4],
                           d_in[5], d_in[6], d_in[7], d_in[8],
                           d_in[9], d_in[10], d_in[11], d_in[12],
                           (const int*)flag, fifo, prog, prog + NP, F, d_out);
    } else {
        hipLaunchKernelGGL(lstm2_mono, dim3(B_ / BT), dim3(BLK), 0, stream,
                           d_in[0], d_in[1], d_in[2], d_in[3], d_in[4],
                           d_in[5], d_in[6], d_in[7], d_in[8],
                           d_in[9], d_in[10], d_in[11], d_in[12],
                           (const int*)flag, d_out);
    }
}